// Round 10
// baseline (152.536 us; speedup 1.0000x reference)
//
#include <hip/hip_runtime.h>
#include <stdint.h>

// SimCLR loss, B=4096, D=512, TAU=0.1.  out[0]=loss, out[1]=acc(%).
//
// Round 20: R19 structure (triangle, amortized reductions, 128 VGPR, no
// spill) with two changes:
//  1. ATOMIC MERGE: tiles accumulates exp-sums straight into SAB[8192]
//     (atomicAdd, after per-wave + LDS-tail partial reduction) and maxes
//     into MaxEnc[4096] (atomicMax on order-preserving uint encoding).
//     Kills the slot arrays: finalize reads 4 values/lane instead of 160
//     strided (measured ~0.07-0.13us/load on its 16-block grid = 10-15us),
//     prep init shrinks 1M -> 12k elements.
//  2. CHUNK=2: every panel I has exactly (64-I) 2-tile chunks -> 2080
//     perfectly balanced blocks (8.1/CU vs R19's ragged 1056 at 14.6%
//     occupancy).  34KB LDS -> 4 blocks/CU resident.
// Kept: __launch_bounds__(256,2) (R18 lesson: never cap below ~115-reg live
// set), 5-bit swizzle (0 conflicts), single 32KB stage buffer, 3-variant
// uniform-branch epilogue, #pragma unroll 1 on tile loop (R12 spill lesson).

#define BN 4096
#define DK 512            // K elements = bytes per row in fp8
#define NEG_BIG -1e30f
#define SCL 0.15625f      // 1/(8*8*TAU)
#define SCL2 0.225396744f // SCL * log2(e)
#define C2 14.4269504f    // 10 * log2(e)
#define TILE_BYTES (64 * DK)  // 32 KB per 64-col fp8 tile
#define NBLK2 2080            // sum_{I=0..63} (64-I)

typedef __attribute__((ext_vector_type(16))) float floatx16;
typedef __attribute__((ext_vector_type(8))) int intx8;

// order-preserving float->uint encoding (monotone over all finite floats)
__device__ __forceinline__ unsigned encf(float f) {
  unsigned u = __float_as_uint(f);
  return ((int)u < 0) ? ~u : (u | 0x80000000u);
}
__device__ __forceinline__ float decf(unsigned u) {
  return (u & 0x80000000u) ? __uint_as_float(u & 0x7FFFFFFFu)
                           : __uint_as_float(~u);
}

// ---------------- prep: normalize, fp8-pack into stacked Gn, init accums --
// Permuted layout per row: byte kc2*32 + h*16 + t*8 + j holds original
// k = kc2*32 + t*16 + h*8 + j (MFMA K=64 operand = chunks 4i+h, 4i+2+h).
__global__ void __launch_bounds__(256) prep_kernel(
    const float* __restrict__ A, const float* __restrict__ Bv,
    unsigned char* __restrict__ Gn, float* __restrict__ diag,
    float* __restrict__ out, float* __restrict__ SAB,
    unsigned* __restrict__ MaxEnc) {
  const int gtid = blockIdx.x * 256 + threadIdx.x;
  if (gtid < 2) out[gtid] = 0.0f;
  if (gtid < 2 * BN) SAB[gtid] = 0.0f;
  if (gtid < BN) MaxEnc[gtid] = encf(NEG_BIG);

  const int w = threadIdx.x >> 6, lane = threadIdx.x & 63;
  const int row = blockIdx.x * 4 + w;
  const float4* pa4 = (const float4*)(A + (size_t)row * DK);
  const float4* pb4 = (const float4*)(Bv + (size_t)row * DK);
  float4 a0 = pa4[lane * 2], a1 = pa4[lane * 2 + 1];  // k = lane*8 .. +7
  float4 b0 = pb4[lane * 2], b1 = pb4[lane * 2 + 1];
  float ssa = a0.x * a0.x + a0.y * a0.y + a0.z * a0.z + a0.w * a0.w +
              a1.x * a1.x + a1.y * a1.y + a1.z * a1.z + a1.w * a1.w;
  float ssb = b0.x * b0.x + b0.y * b0.y + b0.z * b0.z + b0.w * b0.w +
              b1.x * b1.x + b1.y * b1.y + b1.z * b1.z + b1.w * b1.w;
  float sab = a0.x * b0.x + a0.y * b0.y + a0.z * b0.z + a0.w * b0.w +
              a1.x * b1.x + a1.y * b1.y + a1.z * b1.z + a1.w * b1.w;
#pragma unroll
  for (int off = 32; off > 0; off >>= 1) {
    ssa += __shfl_xor(ssa, off);
    ssb += __shfl_xor(ssb, off);
    sab += __shfl_xor(sab, off);
  }
  float na = fmaxf(sqrtf(ssa), 1e-12f);
  float nb = fmaxf(sqrtf(ssb), 1e-12f);
  const float s = 8.0f;  // fp8 pre-scale: keeps elems mid-range in e4m3
  float sa = s / na, sb = s / nb;
  const int doff = (lane >> 2) * 32 + (lane & 1) * 16 + ((lane >> 1) & 1) * 8;
  {
    int v0 = __builtin_amdgcn_cvt_pk_fp8_f32(a0.x * sa, a0.y * sa, 0, false);
    v0 = __builtin_amdgcn_cvt_pk_fp8_f32(a0.z * sa, a0.w * sa, v0, true);
    int v1 = __builtin_amdgcn_cvt_pk_fp8_f32(a1.x * sa, a1.y * sa, 0, false);
    v1 = __builtin_amdgcn_cvt_pk_fp8_f32(a1.z * sa, a1.w * sa, v1, true);
    int2 pv; pv.x = v0; pv.y = v1;
    *(int2*)(Gn + (size_t)row * DK + doff) = pv;
  }
  {
    int v0 = __builtin_amdgcn_cvt_pk_fp8_f32(b0.x * sb, b0.y * sb, 0, false);
    v0 = __builtin_amdgcn_cvt_pk_fp8_f32(b0.z * sb, b0.w * sb, v0, true);
    int v1 = __builtin_amdgcn_cvt_pk_fp8_f32(b1.x * sb, b1.y * sb, 0, false);
    v1 = __builtin_amdgcn_cvt_pk_fp8_f32(b1.z * sb, b1.w * sb, v1, true);
    int2 pv; pv.x = v0; pv.y = v1;
    *(int2*)(Gn + (size_t)(BN + row) * DK + doff) = pv;
  }
  if (lane == 0) diag[row] = (sab / (na * nb)) * 10.0f;  // exact fp32 /TAU
}

// ---------------- tiles: upper-triangle Gram, exactly 2 tiles/block -------
__global__ void __launch_bounds__(256, 2) tiles_kernel(
    const unsigned char* __restrict__ Gn,
    float* __restrict__ SAB, unsigned* __restrict__ MaxEnc) {
  __shared__ __align__(16) unsigned char smem[TILE_BYTES + 2048];

  // decode flat bid -> (I, chunk): panel I has exactly (64-I) 2-tile chunks
  int bid = blockIdx.x, I = 0;
  for (;;) {
    const int nc = 64 - I;
    if (bid < nc) break;
    bid -= nc; ++I;
  }
  const int chunk = bid;
  const int j0 = 2 * I + chunk * 2;

  const int tid = threadIdx.x;
  const int lane = tid & 63, w = tid >> 6;
  const int n5 = lane & 31, h = lane >> 5;
  const int rbase = I * 128 + w * 32;

  // row frags: lane n5 holds row rbase+n5 (once per block)
  intx8 aw[8];
  {
    const unsigned char* p = Gn + (size_t)(rbase + n5) * DK + h * 16;
#pragma unroll
    for (int i = 0; i < 8; ++i) {
      int4 c0 = *(const int4*)(p + i * 64);
      int4 c1 = *(const int4*)(p + i * 64 + 32);
      intx8 v = {c0.x, c0.y, c0.z, c0.w, c1.x, c1.y, c1.z, c1.w};
      aw[i] = v;
    }
  }

  // stage tile j (32 KB): DMA dest linear; 5-bit swizzle via source (phys
  // chunk p of col cl holds logical p^(cl&31))
  auto stage = [&](int j) {
    const int cb = j * 64;
#pragma unroll
    for (int ii = 0; ii < 8; ++ii) {
      const int cp = w * 8 + ii;
      const int cl = cp * 2 + h;
      const unsigned char* src =
          Gn + (size_t)(cb + cl) * DK + ((n5 ^ (cl & 31)) * 16);
      __builtin_amdgcn_global_load_lds(
          (const __attribute__((address_space(1))) void*)src,
          (__attribute__((address_space(3))) void*)(smem + cp * 1024),
          16, 0, 0);
    }
  };

  float l[16], mxr[16];
#pragma unroll
  for (int r = 0; r < 16; ++r) { l[r] = 0.f; mxr[r] = NEG_BIG; }

  float* T = (float*)(smem + TILE_BYTES);  // col-partial tail: [4][64] x2

#pragma unroll 1
  for (int t = 0; t < 2; ++t) {
    const int j = j0 + t;
    stage(j);
    __syncthreads();  // compiler drains vmcnt(0): tile landed for all waves

    floatx16 acc[2];
#pragma unroll
    for (int cs = 0; cs < 2; ++cs)
#pragma unroll
      for (int r = 0; r < 16; ++r) acc[cs][r] = 0.f;

    const unsigned char* bbase = smem + (size_t)n5 * DK;
#pragma unroll
    for (int i = 0; i < 8; ++i) {
      const int p1 = ((4 * i + h) ^ n5) * 16;
      const int p2 = ((4 * i + 2 + h) ^ n5) * 16;
#pragma unroll
      for (int cs = 0; cs < 2; ++cs) {
        int4 b0 = *(const int4*)(bbase + cs * 32 * DK + p1);
        int4 b1 = *(const int4*)(bbase + cs * 32 * DK + p2);
        intx8 bw = {b0.x, b0.y, b0.z, b0.w, b1.x, b1.y, b1.z, b1.w};
        acc[cs] = __builtin_amdgcn_mfma_scale_f32_32x32x64_f8f6f4(
            aw[i], bw, acc[cs], 0, 0, 0, 0x7F7F7F7F, 0, 0x7F7F7F7F);
      }
    }

    // epilogue (3 uniform-branch variants): accumulate row sums/max (regs)
    // + col sums/max (lane-local).  acc elem (r,cs): row rbase+(r&3)+
    // 8(r>>2)+4h, col cbase+cs*32+n5.
    const int cbase = j * 64;
    const bool diagp = ((j >> 1) == I);
    const bool lblp = (I < 32) && (j >= 64);
    const int colg0 = cbase + n5, colg1 = cbase + 32 + n5;
    float csum0 = 0.f, csum1 = 0.f, cmax0 = NEG_BIG, cmax1 = NEG_BIG;

#define EPI_BODY(EXCL0_EXPR, EXCL1_EXPR)                                    \
  _Pragma("unroll")                                                         \
  for (int r = 0; r < 16; ++r) {                                            \
    const int rowg = rbase + (r & 3) + 8 * (r >> 2) + 4 * h;                \
    (void)rowg;                                                             \
    {                                                                       \
      const float v = acc[0][r];                                            \
      const bool excl = (EXCL0_EXPR);                                       \
      const float e = excl ? 0.f : exp2f(fmaf(v, SCL2, -C2));               \
      const float vm = excl ? NEG_BIG : v;                                  \
      l[r] += e; mxr[r] = fmaxf(mxr[r], vm);                                \
      csum0 += e; cmax0 = fmaxf(cmax0, vm);                                 \
    }                                                                       \
    {                                                                       \
      const float v = acc[1][r];                                            \
      const bool excl = (EXCL1_EXPR);                                       \
      const float e = excl ? 0.f : exp2f(fmaf(v, SCL2, -C2));               \
      const float vm = excl ? NEG_BIG : v;                                  \
      l[r] += e; mxr[r] = fmaxf(mxr[r], vm);                                \
      csum1 += e; cmax1 = fmaxf(cmax1, vm);                                 \
    }                                                                       \
  }

    if (diagp) {
      EPI_BODY(colg0 <= rowg, colg1 <= rowg)
    } else if (lblp) {
      EPI_BODY(colg0 == rowg + BN, colg1 == rowg + BN)
    } else {
      EPI_BODY(false, false)
    }
#undef EPI_BODY

    // col partials: combine h-halves, stash in LDS tail, combine x-wave,
    // then ATOMIC merge into the global accumulators.
    csum0 += __shfl_xor(csum0, 32);
    csum1 += __shfl_xor(csum1, 32);
    cmax0 = fmaxf(cmax0, __shfl_xor(cmax0, 32));
    cmax1 = fmaxf(cmax1, __shfl_xor(cmax1, 32));
    float* cps = T;        // [4][64]
    float* cpm = T + 256;  // [4][64]
    if (h == 0) {
      cps[w * 64 + n5] = csum0; cps[w * 64 + 32 + n5] = csum1;
      cpm[w * 64 + n5] = cmax0; cpm[w * 64 + 32 + n5] = cmax1;
    }
    __syncthreads();  // tile reads done (buffer reusable) + cps visible
    if (tid < 64) {
      const float s =
          cps[tid] + cps[64 + tid] + cps[128 + tid] + cps[192 + tid];
      atomicAdd(&SAB[cbase + tid], s);
      if (j < 64) {  // col max only needed for a-cols (q < 4096)
        const float m = fmaxf(fmaxf(cpm[tid], cpm[64 + tid]),
                              fmaxf(cpm[128 + tid], cpm[192 + tid]));
        atomicMax(&MaxEnc[cbase + tid], encf(m));
      }
    }
    // T rewritten only after the next tile's compute (post-sync1); readers
    // consumed it before reaching sync1.
  }

  // one row reduce per block: across the 32 cols (lanes n5), then atomics
#pragma unroll
  for (int off = 1; off < 32; off <<= 1)
#pragma unroll
    for (int r = 0; r < 16; ++r) l[r] += __shfl_xor(l[r], off);
  if (I < 32) {  // row max only needed for a-rows
#pragma unroll
    for (int off = 1; off < 32; off <<= 1)
#pragma unroll
      for (int r = 0; r < 16; ++r)
        mxr[r] = fmaxf(mxr[r], __shfl_xor(mxr[r], off));
  }
  if (n5 == 0) {
#pragma unroll
    for (int r = 0; r < 16; ++r) {
      const int rowg = rbase + (r & 3) + 8 * (r >> 2) + 4 * h;
      atomicAdd(&SAB[rowg], l[r]);
      if (I < 32) atomicMax(&MaxEnc[rowg], encf(mxr[r]));
    }
  }
}

// ---------------- finalize: 4 loads/lane, add label, reduce ---------------
__global__ void __launch_bounds__(256) finalize_kernel(
    const float* __restrict__ SAB, const unsigned* __restrict__ MaxEnc,
    const float* __restrict__ diag, float* __restrict__ out) {
  const int i = blockIdx.x * 256 + threadIdx.x;  // label index, 0..4095
  const float SA = SAB[i];
  const float SB = SAB[BN + i];
  const float MA = decf(MaxEnc[i]) * SCL;  // acc -> logit domain

  const float d = diag[i];
  const float eL = exp2f(fmaf(d, 1.44269504f, -C2));  // exp(d-10)
  float lseA = 10.0f + logf(SA + eL);
  float lseB = 10.0f + logf(SB + eL);
  float lossi = (lseA - d) + (lseB - d);
  float corr = (d >= MA) ? 1.f : 0.f;  // argmax(full_a)==label
#pragma unroll
  for (int off = 32; off > 0; off >>= 1) {
    lossi += __shfl_xor(lossi, off);
    corr += __shfl_xor(corr, off);
  }
  __shared__ float sred[2][4];
  if ((threadIdx.x & 63) == 0) {
    int w = threadIdx.x >> 6;
    sred[0][w] = lossi; sred[1][w] = corr;
  }
  __syncthreads();
  if (threadIdx.x == 0) {
    float ls = sred[0][0] + sred[0][1] + sred[0][2] + sred[0][3];
    float cs = sred[1][0] + sred[1][1] + sred[1][2] + sred[1][3];
    atomicAdd(&out[0], ls * (1.0f / 8192.0f));    // mean over rows, /2
    atomicAdd(&out[1], cs * (100.0f / 4096.0f));  // accuracy %
  }
}

extern "C" void kernel_launch(void* const* d_in, const int* in_sizes, int n_in,
                              void* d_out, int out_size, void* d_ws, size_t ws_size,
                              hipStream_t stream) {
  const float* A = (const float*)d_in[0];
  const float* Bv = (const float*)d_in[1];
  unsigned char* Gn = (unsigned char*)d_ws;          // 8192x512 fp8 (a;b)
  float* diag = (float*)(Gn + (size_t)8192 * DK);    // 4096 f32
  float* SAB = diag + BN;                            // 8192 f32 accum
  unsigned* MaxEnc = (unsigned*)(SAB + 2 * BN);      // 4096 u32 max-encode
  float* out = (float*)d_out;

  prep_kernel<<<BN / 4, 256, 0, stream>>>(A, Bv, Gn, diag, out, SAB, MaxEnc);
  tiles_kernel<<<NBLK2, 256, 0, stream>>>(Gn, SAB, MaxEnc);
  finalize_kernel<<<BN / 256, 256, 0, stream>>>(SAB, MaxEnc, diag, out);
}

// Round 11
// 116.515 us; speedup vs baseline: 1.3091x; 1.3091x over previous
//
#include <hip/hip_runtime.h>
#include <stdint.h>

// SimCLR loss, B=4096, D=512, TAU=0.1.  out[0]=loss, out[1]=acc(%).
//
// Round 21: R19 tiles (best: 49us, no atomics -- R20's atomic merge put
// global-atomic drains inside every barrier's vmcnt(0) wait, +43us) with:
//  1. chunk <= 8 (544 blocks).  R19 occupancy arithmetic: 4.7 waves/CU avg,
//     ~1.2 blocks/CU concurrent -> 1056 blocks ran in ~3.4 sequential
//     rounds of ~14us.  544 bigger blocks fit in ~1.1-1.7 rounds even at 2
//     blocks/CU -> tiles ~30-36us.  Row reductions amortize 2x further.
//  2. PARALLEL finalize: 128 blocks, 8 threads/row (26 loads/thread vs
//     R19's 160/lane on a 16-block grid, measured ~10-15us) -> ~3us.
// Kept: slot arrays + plain stores, 5-bit swizzle (0 conflicts), single
// 32KB stage buffer + LDS tail, 3-variant uniform-branch epilogue,
// __launch_bounds__(256,2) (R18: never cap below live set), unroll-1.

#define BN 4096
#define DK 512            // K elements = bytes per row in fp8
#define NEG_BIG -1e30f
#define SCL 0.15625f      // 1/(8*8*TAU)
#define SCL2 0.225396744f // SCL * log2(e)
#define C2 14.4269504f    // 10 * log2(e)
#define TILE_BYTES (64 * DK)  // 32 KB per 64-col fp8 tile
#define NRS 16                // row-sum slots (max chunks/panel = 128/8)
#define NBLK 544              // sum_{I=0..63} ceil((128-2I)/8)

typedef __attribute__((ext_vector_type(16))) float floatx16;
typedef __attribute__((ext_vector_type(8))) int intx8;

// ---------------- prep: normalize, fp8-pack into stacked Gn, init slots ---
// Permuted layout per row: byte kc2*32 + h*16 + t*8 + j holds original
// k = kc2*32 + t*16 + h*8 + j (MFMA K=64 operand = chunks 4i+h, 4i+2+h).
__global__ void __launch_bounds__(256) prep_kernel(
    const float* __restrict__ A, const float* __restrict__ Bv,
    unsigned char* __restrict__ Gn, float* __restrict__ diag,
    float* __restrict__ out, float* __restrict__ zbase,
    float* __restrict__ mbase) {
  const int gtid = blockIdx.x * 256 + threadIdx.x;
  if (gtid < 2) out[gtid] = 0.0f;
  // zbase = pRS(16*8192)+pCS(64*8192) zeros; mbase = pRM(16*4096)+
  // pCM(32*4096) = NEG_BIG
  for (int idx = gtid; idx < (NRS + 64) * 8192; idx += 1024 * 256)
    zbase[idx] = 0.0f;
  for (int idx = gtid; idx < (NRS + 32) * 4096; idx += 1024 * 256)
    mbase[idx] = NEG_BIG;

  const int w = threadIdx.x >> 6, lane = threadIdx.x & 63;
  const int row = blockIdx.x * 4 + w;
  const float4* pa4 = (const float4*)(A + (size_t)row * DK);
  const float4* pb4 = (const float4*)(Bv + (size_t)row * DK);
  float4 a0 = pa4[lane * 2], a1 = pa4[lane * 2 + 1];  // k = lane*8 .. +7
  float4 b0 = pb4[lane * 2], b1 = pb4[lane * 2 + 1];
  float ssa = a0.x * a0.x + a0.y * a0.y + a0.z * a0.z + a0.w * a0.w +
              a1.x * a1.x + a1.y * a1.y + a1.z * a1.z + a1.w * a1.w;
  float ssb = b0.x * b0.x + b0.y * b0.y + b0.z * b0.z + b0.w * b0.w +
              b1.x * b1.x + b1.y * b1.y + b1.z * b1.z + b1.w * b1.w;
  float sab = a0.x * b0.x + a0.y * b0.y + a0.z * b0.z + a0.w * b0.w +
              a1.x * b1.x + a1.y * b1.y + a1.z * b1.z + a1.w * b1.w;
#pragma unroll
  for (int off = 32; off > 0; off >>= 1) {
    ssa += __shfl_xor(ssa, off);
    ssb += __shfl_xor(ssb, off);
    sab += __shfl_xor(sab, off);
  }
  float na = fmaxf(sqrtf(ssa), 1e-12f);
  float nb = fmaxf(sqrtf(ssb), 1e-12f);
  const float s = 8.0f;  // fp8 pre-scale: keeps elems mid-range in e4m3
  float sa = s / na, sb = s / nb;
  const int doff = (lane >> 2) * 32 + (lane & 1) * 16 + ((lane >> 1) & 1) * 8;
  {
    int v0 = __builtin_amdgcn_cvt_pk_fp8_f32(a0.x * sa, a0.y * sa, 0, false);
    v0 = __builtin_amdgcn_cvt_pk_fp8_f32(a0.z * sa, a0.w * sa, v0, true);
    int v1 = __builtin_amdgcn_cvt_pk_fp8_f32(a1.x * sa, a1.y * sa, 0, false);
    v1 = __builtin_amdgcn_cvt_pk_fp8_f32(a1.z * sa, a1.w * sa, v1, true);
    int2 pv; pv.x = v0; pv.y = v1;
    *(int2*)(Gn + (size_t)row * DK + doff) = pv;
  }
  {
    int v0 = __builtin_amdgcn_cvt_pk_fp8_f32(b0.x * sb, b0.y * sb, 0, false);
    v0 = __builtin_amdgcn_cvt_pk_fp8_f32(b0.z * sb, b0.w * sb, v0, true);
    int v1 = __builtin_amdgcn_cvt_pk_fp8_f32(b1.x * sb, b1.y * sb, 0, false);
    v1 = __builtin_amdgcn_cvt_pk_fp8_f32(b1.z * sb, b1.w * sb, v1, true);
    int2 pv; pv.x = v0; pv.y = v1;
    *(int2*)(Gn + (size_t)(BN + row) * DK + doff) = pv;
  }
  if (lane == 0) diag[row] = (sab / (na * nb)) * 10.0f;  // exact fp32 /TAU
}

// ---------------- tiles: upper-triangle Gram, <=8 tiles/block, 34KB LDS ---
__global__ void __launch_bounds__(256, 2) tiles_kernel(
    const unsigned char* __restrict__ Gn,
    float* __restrict__ pRS, float* __restrict__ pCS,
    float* __restrict__ pRM, float* __restrict__ pCM) {
  __shared__ __align__(16) unsigned char smem[TILE_BYTES + 2048];

  // decode flat bid -> (I, chunk): panel I has ceil((128-2I)/8) chunks
  int bid = blockIdx.x, I = 0;
  for (;;) {
    const int nc = (135 - 2 * I) >> 3;
    if (bid < nc) break;
    bid -= nc; ++I;
  }
  const int chunk = bid;
  const int j0 = 2 * I + chunk * 8;
  const int ntiles = min(8, 128 - 2 * I - chunk * 8);

  const int tid = threadIdx.x;
  const int lane = tid & 63, w = tid >> 6;
  const int n5 = lane & 31, h = lane >> 5;
  const int rbase = I * 128 + w * 32;

  // row frags: lane n5 holds row rbase+n5 (once per block)
  intx8 aw[8];
  {
    const unsigned char* p = Gn + (size_t)(rbase + n5) * DK + h * 16;
#pragma unroll
    for (int i = 0; i < 8; ++i) {
      int4 c0 = *(const int4*)(p + i * 64);
      int4 c1 = *(const int4*)(p + i * 64 + 32);
      intx8 v = {c0.x, c0.y, c0.z, c0.w, c1.x, c1.y, c1.z, c1.w};
      aw[i] = v;
    }
  }

  // stage tile j (32 KB): DMA dest linear; 5-bit swizzle via source (phys
  // chunk p of col cl holds logical p^(cl&31))
  auto stage = [&](int j) {
    const int cb = j * 64;
#pragma unroll
    for (int ii = 0; ii < 8; ++ii) {
      const int cp = w * 8 + ii;
      const int cl = cp * 2 + h;
      const unsigned char* src =
          Gn + (size_t)(cb + cl) * DK + ((n5 ^ (cl & 31)) * 16);
      __builtin_amdgcn_global_load_lds(
          (const __attribute__((address_space(1))) void*)src,
          (__attribute__((address_space(3))) void*)(smem + cp * 1024),
          16, 0, 0);
    }
  };

  float l[16], mxr[16];
#pragma unroll
  for (int r = 0; r < 16; ++r) { l[r] = 0.f; mxr[r] = NEG_BIG; }

  float* T = (float*)(smem + TILE_BYTES);  // col-partial tail: [4][64] x2

#pragma unroll 1
  for (int t = 0; t < ntiles; ++t) {
    const int j = j0 + t;
    stage(j);
    __syncthreads();  // compiler drains vmcnt(0): tile landed for all waves

    floatx16 acc[2];
#pragma unroll
    for (int cs = 0; cs < 2; ++cs)
#pragma unroll
      for (int r = 0; r < 16; ++r) acc[cs][r] = 0.f;

    const unsigned char* bbase = smem + (size_t)n5 * DK;
#pragma unroll
    for (int i = 0; i < 8; ++i) {
      const int p1 = ((4 * i + h) ^ n5) * 16;
      const int p2 = ((4 * i + 2 + h) ^ n5) * 16;
#pragma unroll
      for (int cs = 0; cs < 2; ++cs) {
        int4 b0 = *(const int4*)(bbase + cs * 32 * DK + p1);
        int4 b1 = *(const int4*)(bbase + cs * 32 * DK + p2);
        intx8 bw = {b0.x, b0.y, b0.z, b0.w, b1.x, b1.y, b1.z, b1.w};
        acc[cs] = __builtin_amdgcn_mfma_scale_f32_32x32x64_f8f6f4(
            aw[i], bw, acc[cs], 0, 0, 0, 0x7F7F7F7F, 0, 0x7F7F7F7F);
      }
    }

    // epilogue (3 uniform-branch variants): accumulate row sums/max (regs)
    // + col sums/max (lane-local).  acc elem (r,cs): row rbase+(r&3)+
    // 8(r>>2)+4h, col cbase+cs*32+n5.
    const int cbase = j * 64;
    const bool diagp = ((j >> 1) == I);
    const bool lblp = (I < 32) && (j >= 64);
    const int colg0 = cbase + n5, colg1 = cbase + 32 + n5;
    float csum0 = 0.f, csum1 = 0.f, cmax0 = NEG_BIG, cmax1 = NEG_BIG;

#define EPI_BODY(EXCL0_EXPR, EXCL1_EXPR)                                    \
  _Pragma("unroll")                                                         \
  for (int r = 0; r < 16; ++r) {                                            \
    const int rowg = rbase + (r & 3) + 8 * (r >> 2) + 4 * h;                \
    (void)rowg;                                                             \
    {                                                                       \
      const float v = acc[0][r];                                            \
      const bool excl = (EXCL0_EXPR);                                       \
      const float e = excl ? 0.f : exp2f(fmaf(v, SCL2, -C2));               \
      const float vm = excl ? NEG_BIG : v;                                  \
      l[r] += e; mxr[r] = fmaxf(mxr[r], vm);                                \
      csum0 += e; cmax0 = fmaxf(cmax0, vm);                                 \
    }                                                                       \
    {                                                                       \
      const float v = acc[1][r];                                            \
      const bool excl = (EXCL1_EXPR);                                       \
      const float e = excl ? 0.f : exp2f(fmaf(v, SCL2, -C2));               \
      const float vm = excl ? NEG_BIG : v;                                  \
      l[r] += e; mxr[r] = fmaxf(mxr[r], vm);                                \
      csum1 += e; cmax1 = fmaxf(cmax1, vm);                                 \
    }                                                                       \
  }

    if (diagp) {
      EPI_BODY(colg0 <= rowg, colg1 <= rowg)
    } else if (lblp) {
      EPI_BODY(colg0 == rowg + BN, colg1 == rowg + BN)
    } else {
      EPI_BODY(false, false)
    }
#undef EPI_BODY

    // col partials: combine h-halves, stash in LDS tail, combine x-wave
    csum0 += __shfl_xor(csum0, 32);
    csum1 += __shfl_xor(csum1, 32);
    cmax0 = fmaxf(cmax0, __shfl_xor(cmax0, 32));
    cmax1 = fmaxf(cmax1, __shfl_xor(cmax1, 32));
    float* cps = T;        // [4][64]
    float* cpm = T + 256;  // [4][64]
    if (h == 0) {
      cps[w * 64 + n5] = csum0; cps[w * 64 + 32 + n5] = csum1;
      cpm[w * 64 + n5] = cmax0; cpm[w * 64 + 32 + n5] = cmax1;
    }
    __syncthreads();  // tile reads done (buffer reusable) + cps visible
    if (tid < 64) {
      const float s =
          cps[tid] + cps[64 + tid] + cps[128 + tid] + cps[192 + tid];
      pCS[(size_t)I * 8192 + cbase + tid] = s;
      if (j < 64) {  // col max only needed for a-cols (q < 4096)
        const float m = fmaxf(fmaxf(cpm[tid], cpm[64 + tid]),
                              fmaxf(cpm[128 + tid], cpm[192 + tid]));
        pCM[(size_t)I * 4096 + cbase + tid] = m;
      }
    }
    // T rewritten only after the next tile's post-stage __syncthreads;
    // readers consumed it before reaching that barrier.
  }

  // one row reduce per block: across the 32 cols (lanes n5)
#pragma unroll
  for (int off = 1; off < 32; off <<= 1)
#pragma unroll
    for (int r = 0; r < 16; ++r) l[r] += __shfl_xor(l[r], off);
  if (I < 32) {  // row max only needed for a-rows
#pragma unroll
    for (int off = 1; off < 32; off <<= 1)
#pragma unroll
      for (int r = 0; r < 16; ++r)
        mxr[r] = fmaxf(mxr[r], __shfl_xor(mxr[r], off));
  }
  if (n5 == 0) {
#pragma unroll
    for (int r = 0; r < 16; ++r) {
      const int rowg = rbase + (r & 3) + 8 * (r >> 2) + 4 * h;
      pRS[(size_t)chunk * 8192 + rowg] = l[r];
      if (I < 32) pRM[(size_t)chunk * 4096 + rowg] = mxr[r];
    }
  }
}

// ---------------- finalize: 8 threads/row, parallel slot merge ------------
__global__ void __launch_bounds__(256) finalize_kernel(
    const float* __restrict__ pRS, const float* __restrict__ pCS,
    const float* __restrict__ pRM, const float* __restrict__ pCM,
    const float* __restrict__ diag, float* __restrict__ out) {
  const int k = threadIdx.x & 7;        // slot-share index, 0..7
  const int r = threadIdx.x >> 3;       // row within block, 0..31
  const int i = blockIdx.x * 32 + r;    // label index, 0..4095

  float SA = 0.f, SB = 0.f, MA = NEG_BIG;
#pragma unroll
  for (int q = 0; q < 2; ++q) {         // pRS/pRM: 16 slots, 2 per thread
    const int s = k * 2 + q;
    SA += pRS[(size_t)s * 8192 + i];
    SB += pRS[(size_t)s * 8192 + BN + i];
    MA = fmaxf(MA, pRM[(size_t)s * 4096 + i]);
  }
#pragma unroll
  for (int q = 0; q < 8; ++q) {         // pCS: 64 slots, 8 per thread
    const int s = k * 8 + q;
    SA += pCS[(size_t)s * 8192 + i];
    SB += pCS[(size_t)s * 8192 + BN + i];
  }
#pragma unroll
  for (int q = 0; q < 4; ++q) {         // pCM: 32 slots, 4 per thread
    const int s = k * 4 + q;
    MA = fmaxf(MA, pCM[(size_t)s * 4096 + i]);
  }
  // combine the 8-thread group (lanes k=0..7 of the same row)
#pragma unroll
  for (int off = 1; off < 8; off <<= 1) {
    SA += __shfl_xor(SA, off);
    SB += __shfl_xor(SB, off);
    MA = fmaxf(MA, __shfl_xor(MA, off));
  }

  float lossi = 0.f, corr = 0.f;
  if (k == 0) {
    const float d = diag[i];
    const float eL = exp2f(fmaf(d, 1.44269504f, -C2));  // exp(d-10)
    lossi = (10.0f + logf(SA + eL) - d) + (10.0f + logf(SB + eL) - d);
    corr = (d >= MA * SCL) ? 1.f : 0.f;  // argmax(full_a)==label
  }
#pragma unroll
  for (int off = 32; off > 0; off >>= 1) {
    lossi += __shfl_xor(lossi, off);
    corr += __shfl_xor(corr, off);
  }
  __shared__ float sred[2][4];
  if ((threadIdx.x & 63) == 0) {
    int w = threadIdx.x >> 6;
    sred[0][w] = lossi; sred[1][w] = corr;
  }
  __syncthreads();
  if (threadIdx.x == 0) {
    float ls = sred[0][0] + sred[0][1] + sred[0][2] + sred[0][3];
    float cs = sred[1][0] + sred[1][1] + sred[1][2] + sred[1][3];
    atomicAdd(&out[0], ls * (1.0f / 8192.0f));    // mean over rows, /2
    atomicAdd(&out[1], cs * (100.0f / 4096.0f));  // accuracy %
  }
}

extern "C" void kernel_launch(void* const* d_in, const int* in_sizes, int n_in,
                              void* d_out, int out_size, void* d_ws, size_t ws_size,
                              hipStream_t stream) {
  const float* A = (const float*)d_in[0];
  const float* Bv = (const float*)d_in[1];
  unsigned char* Gn = (unsigned char*)d_ws;          // 8192x512 fp8 (a;b)
  float* diag = (float*)(Gn + (size_t)8192 * DK);    // 4096 f32
  float* pRS = diag + BN;                            // [16][8192]
  float* pCS = pRS + NRS * 8192;                     // [64][8192]
  float* pRM = pCS + 64 * 8192;                      // [16][4096]
  float* pCM = pRM + NRS * 4096;                     // [32][4096]
  float* out = (float*)d_out;

  prep_kernel<<<BN / 4, 256, 0, stream>>>(A, Bv, Gn, diag, out, pRS, pRM);
  tiles_kernel<<<NBLK, 256, 0, stream>>>(Gn, pRS, pCS, pRM, pCM);
  finalize_kernel<<<BN / 32, 256, 0, stream>>>(pRS, pCS, pRM, pCM, diag, out);
}